// Round 5
// baseline (1202.886 us; speedup 1.0000x reference)
//
#include <hip/hip_runtime.h>
#include <hip/hip_bf16.h>
#include <math.h>

#define T_TOK 2048
#define DM    1024
#define DF    4096
#define NE    8
#define BM    256         // m-supertile: 2 subtiles of 128 sharing one B tile
#define BN    128
#define BK    32          // 64 B per row per k-tile
#define PAD   256         // expert list padding

typedef __attribute__((ext_vector_type(8))) short          bf16x8;
typedef __attribute__((ext_vector_type(8))) unsigned short ushort8;
typedef __attribute__((ext_vector_type(4))) float          f32x4;

__device__ __forceinline__ unsigned short f2bf(float f) {
  unsigned u = __builtin_bit_cast(unsigned, f);
  unsigned r = u + 0x7fffu + ((u >> 16) & 1u);   // RNE
  return (unsigned short)(r >> 16);
}

// ---------------- x f32 -> bf16 ----------------
__global__ void convert_x_kernel(const float* __restrict__ x, unsigned short* __restrict__ xb) {
  int i = blockIdx.x * blockDim.x + threadIdx.x;
  const float* src = x + (size_t)i * 8;
  float4 a = *(const float4*)(src);
  float4 b = *(const float4*)(src + 4);
  ushort8 v;
  v[0] = f2bf(a.x); v[1] = f2bf(a.y); v[2] = f2bf(a.z); v[3] = f2bf(a.w);
  v[4] = f2bf(b.x); v[5] = f2bf(b.y); v[6] = f2bf(b.z); v[7] = f2bf(b.w);
  *(ushort8*)(xb + (size_t)i * 8) = v;
}

// ---------------- weight convert + transpose: W[E][K][N] f32 -> Wt[E][N][K] bf16 ----------------
template<int K, int N>
__global__ __launch_bounds__(256) void transpose_convert(
    const float* __restrict__ W, unsigned short* __restrict__ Wt)
{
  const int e  = blockIdx.z;
  const int k0 = blockIdx.y * 32;
  const int n0 = blockIdx.x * 128;
  const float* Wp = W + (size_t)e * K * N;
  unsigned short* Wo = Wt + (size_t)e * N * K;
  __shared__ float Ls[32][132];
  const int tid = threadIdx.x;
  {
    const int kl = tid >> 5;
    const int nl = (tid & 31) * 4;
#pragma unroll
    for (int p = 0; p < 4; p++) {
      const int k = kl + p * 8;
      float4 v = *(const float4*)(Wp + (size_t)(k0 + k) * N + n0 + nl);
      *(float4*)&Ls[k][nl] = v;
    }
  }
  __syncthreads();
  {
    const int n  = tid & 127;
    const int c0 = tid >> 7;
#pragma unroll
    for (int p = 0; p < 2; p++) {
      const int c = c0 + p * 2;
      ushort8 o;
#pragma unroll
      for (int j = 0; j < 8; j++) o[j] = f2bf(Ls[c * 8 + j][n]);
      *(ushort8*)(Wo + (size_t)(n0 + n) * K + k0 + c * 8) = o;
    }
  }
}

// ---------------- gating: one wave per token ----------------
__global__ __launch_bounds__(256) void gating_kernel(
    const float* __restrict__ x, const float* __restrict__ wg, const float* __restrict__ bg,
    int* __restrict__ cnt, int* __restrict__ perm, float* __restrict__ pw)
{
  int wid  = (blockIdx.x * blockDim.x + threadIdx.x) >> 6;
  int lane = threadIdx.x & 63;
  if (wid >= T_TOK) return;
  const float* xr = x + (size_t)wid * DM;

  float acc[NE];
#pragma unroll
  for (int e = 0; e < NE; e++) acc[e] = 0.f;
  for (int d = lane; d < DM; d += 64) {
    float xv = xr[d];
    const float* wr = wg + (size_t)d * NE;
#pragma unroll
    for (int e = 0; e < NE; e++) acc[e] += xv * wr[e];
  }
#pragma unroll
  for (int off = 32; off > 0; off >>= 1) {
#pragma unroll
    for (int e = 0; e < NE; e++) acc[e] += __shfl_xor(acc[e], off, 64);
  }
  if (lane == 0) {
    float v[NE];
#pragma unroll
    for (int e = 0; e < NE; e++) v[e] = acc[e] + bg[e];
    int i0 = 0; float v0 = v[0];
#pragma unroll
    for (int e = 1; e < NE; e++) { if (v[e] > v0) { v0 = v[e]; i0 = e; } }
    int i1 = -1; float v1 = -INFINITY;
#pragma unroll
    for (int e = 0; e < NE; e++) { if (e != i0 && v[e] > v1) { v1 = v[e]; i1 = e; } }
    float e1 = expf(v1 - v0);
    float s  = 1.f + e1;
    float w0 = 1.f / s, w1 = e1 / s;
    int p0 = atomicAdd(&cnt[i0], 1);
    perm[i0 * T_TOK + p0] = wid; pw[i0 * T_TOK + p0] = w0;
    int p1 = atomicAdd(&cnt[i1], 1);
    perm[i1 * T_TOK + p1] = wid; pw[i1 * T_TOK + p1] = w1;
  }
}

// ---------------- pad lists to PAD multiple + exclusive scan ----------------
__global__ void pad_scan_kernel(const int* __restrict__ cnt, int* __restrict__ cntpad,
                                int* __restrict__ offs, int* __restrict__ perm, float* __restrict__ pw)
{
  if (threadIdx.x == 0) {
    int o = 0;
    for (int e = 0; e < NE; e++) {
      int c  = cnt[e];
      int cp = (c + PAD - 1) / PAD * PAD;
      cntpad[e] = cp;
      offs[e]   = o;
      o += cp;
    }
    offs[NE] = o;
  }
  for (int e = 0; e < NE; e++) {
    int c  = cnt[e];
    int cp = (c + PAD - 1) / PAD * PAD;
    for (int i = c + threadIdx.x; i < cp; i += blockDim.x) {
      perm[e * T_TOK + i] = 0;
      pw[e * T_TOK + i]   = 0.f;
    }
  }
}

// ======== v5 GEMM: 256x128 supertile, 4 waves, single LDS buffer, 2-deep reg prefetch ========
// LDS layout per row: 4 chunks of 16B, chunk slot = (k4 ^ ((row>>1)&3)) -> 0-conflict b128 (r4-verified)
template<int PHASE, int KTOT, int NCOLS, int KSPLIT>
__global__ __launch_bounds__(256, 2) void moe_gemm5(
    const unsigned short* __restrict__ Asrc,
    const unsigned short* __restrict__ Bt,     // [E][NCOLS][KTOT] bf16
    const float* __restrict__ bias,
    const int* __restrict__ cntpad, const int* __restrict__ offs,
    const int* __restrict__ perm, const float* __restrict__ pw,
    unsigned short* __restrict__ Hout, float* __restrict__ out)
{
  const int e  = blockIdx.z;
  const int mt = blockIdx.y;
  const int nt = blockIdx.x / KSPLIT;
  const int ks = blockIdx.x % KSPLIT;
  const int cp = cntpad[e];
  if (mt * BM >= cp) return;
  const int tid = threadIdx.x;
  const int oe  = offs[e];

  __shared__ __align__(16) unsigned short As[BM * BK];   // 16 KB
  __shared__ __align__(16) unsigned short Bs[BN * BK];   // 8 KB

  const int wid  = tid >> 6;
  const int lane = tid & 63;
  const int kbase0 = ks * (KTOT / KSPLIT);
  const int KITERS = (KTOT / KSPLIT) / BK;   // 32 both phases

  // ---- staging tasks: 16 rows x 4 chunks of 16B per wave-instruction ----
  // A: 4 issues (256 rows), B: 2 issues (128 rows). global chunk = lane&3, LDS slot = chunk^((r>>1)&3)
  const unsigned short* agp[4];
  int aw[4];
#pragma unroll
  for (int i = 0; i < 4; i++) {
    const int r = wid * 64 + i * 16 + (lane >> 2);
    const int g = lane & 3;
    size_t arow;
    if (PHASE == 1) {
      int token = perm[e * T_TOK + mt * BM + r];
      arow = (size_t)token * KTOT;
    } else {
      arow = (size_t)(oe + mt * BM + r) * (size_t)KTOT;
    }
    agp[i] = Asrc + arow + kbase0 + g * 8;
    aw[i]  = r * BK + ((g ^ ((r >> 1) & 3)) * 8);
  }
  const unsigned short* bgp[2];
  int bw[2];
#pragma unroll
  for (int i = 0; i < 2; i++) {
    const int r = wid * 32 + i * 16 + (lane >> 2);
    const int g = lane & 3;
    bgp[i] = Bt + ((size_t)e * NCOLS + (size_t)nt * BN + r) * KTOT + kbase0 + g * 8;
    bw[i]  = r * BK + ((g ^ ((r >> 1) & 3)) * 8);
  }

  // ---- fragment offsets (ushort idx), XOR-swizzled ----
  const int wm = (wid & 1) * 64;
  const int wn = (wid >> 1) * 64;
  int faOff[2][4], fbOff[4];
#pragma unroll
  for (int s = 0; s < 2; s++)
#pragma unroll
    for (int i = 0; i < 4; i++) {
      const int ra = s * 128 + wm + i * 16 + (lane & 15);
      faOff[s][i] = ra * BK + (((lane >> 4) ^ ((ra >> 1) & 3)) * 8);
    }
#pragma unroll
  for (int j = 0; j < 4; j++) {
    const int rb = wn + j * 16 + (lane & 15);
    fbOff[j] = rb * BK + (((lane >> 4) ^ ((rb >> 1) & 3)) * 8);
  }

  f32x4 acc[2][4][4];
#pragma unroll
  for (int s = 0; s < 2; s++)
#pragma unroll
    for (int i = 0; i < 4; i++)
#pragma unroll
      for (int j = 0; j < 4; j++) acc[s][i][j] = (f32x4){0.f, 0.f, 0.f, 0.f};

  uint4 pa[2][4], pb[2][2];   // two prefetch sets

#define LOADT(st, kt) do { \
    _Pragma("unroll") for (int i = 0; i < 4; i++) pa[st][i] = *(const uint4*)(agp[i] + (size_t)(kt) * BK); \
    _Pragma("unroll") for (int i = 0; i < 2; i++) pb[st][i] = *(const uint4*)(bgp[i] + (size_t)(kt) * BK); \
  } while (0)
#define STORET(st) do { \
    _Pragma("unroll") for (int i = 0; i < 4; i++) *(uint4*)&As[aw[i]] = pa[st][i]; \
    _Pragma("unroll") for (int i = 0; i < 2; i++) *(uint4*)&Bs[bw[i]] = pb[st][i]; \
  } while (0)

  LOADT(0, 0);
  STORET(0);
  LOADT(1, 1);

  for (int kt = 0; kt < KITERS; kt++) {
    __syncthreads();                               // staging writes visible
    if (kt + 2 < KITERS) LOADT(kt & 1, kt + 2);    // reuse the set already flushed to LDS
    // compute tile kt
    {
      bf16x8 bfv[4];
#pragma unroll
      for (int j = 0; j < 4; j++) bfv[j] = *(const bf16x8*)&Bs[fbOff[j]];
#pragma unroll
      for (int s = 0; s < 2; s++) {
        bf16x8 af[4];
#pragma unroll
        for (int i = 0; i < 4; i++) af[i] = *(const bf16x8*)&As[faOff[s][i]];
#pragma unroll
        for (int i = 0; i < 4; i++)
#pragma unroll
          for (int j = 0; j < 4; j++)
            acc[s][i][j] = __builtin_amdgcn_mfma_f32_16x16x32_bf16(af[i], bfv[j], acc[s][i][j], 0, 0, 0);
      }
    }
    __syncthreads();                               // frag reads done; LDS reusable
    if (kt + 1 < KITERS) STORET((kt + 1) & 1);
  }

#undef LOADT
#undef STORET

  // epilogue: C/D layout col=lane&15, row=(lane>>4)*4+reg
  const int crow = (lane >> 4) * 4;
  const int ccol = lane & 15;
#pragma unroll
  for (int s = 0; s < 2; s++) {
#pragma unroll
    for (int j = 0; j < 4; j++) {
      const int gn = nt * BN + wn + j * 16 + ccol;
      const float bv = bias[e * NCOLS + gn];
#pragma unroll
      for (int i = 0; i < 4; i++) {
#pragma unroll
        for (int r = 0; r < 4; r++) {
          const int lm = s * 128 + wm + i * 16 + crow + r;
          float v = acc[s][i][j][r];
          if (PHASE == 1) {
            v += bv;
            v = v > 0.f ? v : 0.f;
            Hout[(size_t)(oe + mt * BM + lm) * NCOLS + gn] = f2bf(v);
          } else {
            if (ks == 0) v += bv;
            const int li    = e * T_TOK + mt * BM + lm;
            const int token = perm[li];
            const float w   = pw[li];
            atomicAdd(&out[(size_t)token * NCOLS + gn], w * v);
          }
        }
      }
    }
  }
}

extern "C" void kernel_launch(void* const* d_in, const int* in_sizes, int n_in,
                              void* d_out, int out_size, void* d_ws, size_t ws_size,
                              hipStream_t stream) {
  const float* x  = (const float*)d_in[0];
  const float* wg = (const float*)d_in[1];
  const float* bg = (const float*)d_in[2];
  const float* w1 = (const float*)d_in[3];
  const float* b1 = (const float*)d_in[4];
  const float* w2 = (const float*)d_in[5];
  const float* b2 = (const float*)d_in[6];
  float* out = (float*)d_out;

  const size_t XB_BYTES   = (size_t)T_TOK * DM * 2;
  const size_t PERM_BYTES = (size_t)NE * T_TOK * 4;
  const size_t PW_BYTES   = (size_t)NE * T_TOK * 4;
  const size_t H_BYTES    = (size_t)(2 * T_TOK + NE * PAD) * DF * 2;   // up to 6144 rows
  const size_t W1T_BYTES  = (size_t)NE * DF * DM * 2;

  char* wsp = (char*)d_ws;
  size_t off = 0;
  unsigned short* xb = (unsigned short*)(wsp + off); off += XB_BYTES;
  int*   cnt    = (int*)(wsp + off); off += 256;
  int*   cntpad = cnt + 8;
  int*   offs   = cnt + 16;
  int*   perm   = (int*)(wsp + off);   off += PERM_BYTES;
  float* pwt    = (float*)(wsp + off); off += PW_BYTES;
  unsigned short* H   = (unsigned short*)(wsp + off); off += H_BYTES;
  unsigned short* w1t = (unsigned short*)(wsp + off); off += W1T_BYTES;
  unsigned short* w2t = (unsigned short*)(wsp + off);

  hipMemsetAsync(cnt, 0, 256, stream);
  hipMemsetAsync(d_out, 0, (size_t)T_TOK * DM * 4, stream);

  convert_x_kernel<<<(T_TOK * DM / 8) / 256, 256, 0, stream>>>(x, xb);
  gating_kernel<<<T_TOK / 4, 256, 0, stream>>>(x, wg, bg, cnt, perm, pwt);
  pad_scan_kernel<<<1, 256, 0, stream>>>(cnt, cntpad, offs, perm, pwt);

  transpose_convert<DM, DF><<<dim3(DF / 128, DM / 32, NE), 256, 0, stream>>>(w1, w1t);
  transpose_convert<DF, DM><<<dim3(DM / 128, DF / 32, NE), 256, 0, stream>>>(w2, w2t);

  // phase 1: KITERS=32 (K=1024). grid x=32 ntiles (x%8==0 keeps same-(e,nt) mt's on one XCD)
  moe_gemm5<1, DM, DF, 1><<<dim3(DF / BN, T_TOK / BM, NE), 256, 0, stream>>>(
      xb, w1t, b1, cntpad, offs, perm, pwt, H, nullptr);
  // phase 2: KSPLIT=4 -> KITERS=32, grid x=32
  moe_gemm5<2, DF, DM, 4><<<dim3((DM / BN) * 4, T_TOK / BM, NE), 256, 0, stream>>>(
      H, w2t, b2, cntpad, offs, perm, pwt, nullptr, out);
}